// Round 1
// baseline (98.501 us; speedup 1.0000x reference)
//
#include <hip/hip_runtime.h>
#include <cstddef>

#define EPS 1e-6f
constexpr float INV_SQRT_E = 0.6065306597126334f;  // exp(-0.5*THETA^2), THETA=1

// One kernel instantiation per dilation D.
// Tile: 64 wide x 16 tall per block; block = (64,4) threads, each thread does
// 4 rows (stride 4). All compute-phase LDS reads are 64 consecutive floats
// across the wave -> 2 lanes/bank -> conflict-free.
template <int D>
__global__ __launch_bounds__(256) void tex_kernel(
    const float* __restrict__ x, float* __restrict__ out, int H, int W)
{
    constexpr int PAD = D * D;          // halo per side
    constexpr int KS  = 2 * D + 1;      // taps per axis (k)
    constexpr int K   = KS * KS;        // patch size
    constexpr int TW  = 64, TH = 16;
    constexpr int LW  = TW + 2 * PAD;
    constexpr int LH  = TH + 2 * PAD;
    constexpr float INVK = 1.0f / (float)K;
    constexpr float UNB  = (float)K / (float)(K - 1);  // unbiased correction

    __shared__ float sx [LH * LW];   // input values (zero-padded halo)
    __shared__ float slg[LH * LW];   // x * log(x + eps), precomputed once

    const int bc = blockIdx.z;               // b*C + c
    const int w0 = blockIdx.x * TW;
    const int h0 = blockIdx.y * TH;
    const float* xp = x + (size_t)bc * H * W;

    // Cooperative staging of tile + halo (zeros outside the image).
    const int tid = threadIdx.y * 64 + threadIdx.x;
    for (int idx = tid; idx < LH * LW; idx += 256) {
        const int r  = idx / LW;             // const divisor -> magic mul
        const int cc = idx - r * LW;
        const int gh = h0 - PAD + r;
        const int gw = w0 - PAD + cc;
        float v = 0.0f;
        if (gh >= 0 && gh < H && gw >= 0 && gw < W) v = xp[gh * W + gw];
        sx[idx]  = v;
        slg[idx] = v * __logf(v + EPS);      // v=0 -> exactly 0 (matches ref pad)
    }
    __syncthreads();

    const int tx = threadIdx.x;
    const size_t fstride = (size_t)H * W;
    float* op = out + (size_t)bc * 4 * fstride + w0 + tx;

    for (int r = 0; r < 4; ++r) {
        const int iy = threadIdx.y + r * 4;  // local output row in tile

        // Pass 1: sum, sum of squares, sum of p*log(p+eps)
        float s = 0.0f, s2 = 0.0f, sl = 0.0f;
        for (int mi = 0; mi < KS; ++mi) {
            const float* rx = &sx [(iy + mi * D) * LW + tx];
            const float* rl = &slg[(iy + mi * D) * LW + tx];
            #pragma unroll
            for (int mj = 0; mj < KS; ++mj) {
                const float v = rx[mj * D];
                s  += v;
                s2  = fmaf(v, v, s2);
                sl += rl[mj * D];
            }
        }
        const float mu = s * INVK;

        // Pass 2: sum |p - mu| (not separable; mu is per-pixel)
        float sad = 0.0f;
        for (int mi = 0; mi < KS; ++mi) {
            const float* rx = &sx[(iy + mi * D) * LW + tx];
            #pragma unroll
            for (int mj = 0; mj < KS; ++mj)
                sad += fabsf(rx[mj * D] - mu);
        }

        const float energy   = s2 * INVK;
        const float var      = fmaxf(energy - mu * mu, 0.0f);  // E[p^2]-mu^2
        const float sd       = sqrtf(var * UNB) + EPS;
        const float contrast = var / (sd * sd);
        const float entropy  = -sl * INVK;
        const float homog    = 1.0f / (1.0f + sad * INVK);

        const int    h      = h0 + iy;
        const size_t rowoff = (size_t)h * W;
        // M = exp(log(f+eps) - 0.5) = (f+eps)*e^{-0.5}
        op[0 * fstride + rowoff] = (contrast + EPS) * INV_SQRT_E;
        op[1 * fstride + rowoff] = (energy   + EPS) * INV_SQRT_E;
        op[2 * fstride + rowoff] = (entropy  + EPS) * INV_SQRT_E;
        op[3 * fstride + rowoff] = (homog    + EPS) * INV_SQRT_E;
    }
}

extern "C" void kernel_launch(void* const* d_in, const int* in_sizes, int n_in,
                              void* d_out, int out_size, void* d_ws, size_t ws_size,
                              hipStream_t stream) {
    const float* x = (const float*)d_in[0];
    float* out = (float*)d_out;

    const int B = 2, C = 4, H = 256, W = 256;   // fixed by setup_inputs()
    const size_t per = (size_t)B * C * 4 * H * W;  // elems per dilation output

    dim3 blk(64, 4, 1);
    dim3 grd(W / 64, H / 16, B * C);
    tex_kernel<1><<<grd, blk, 0, stream>>>(x, out + 0 * per, H, W);
    tex_kernel<2><<<grd, blk, 0, stream>>>(x, out + 1 * per, H, W);
    tex_kernel<3><<<grd, blk, 0, stream>>>(x, out + 2 * per, H, W);
    tex_kernel<4><<<grd, blk, 0, stream>>>(x, out + 3 * per, H, W);
}